// Round 1
// baseline (383.272 us; speedup 1.0000x reference)
//
#include <hip/hip_runtime.h>

// DecomposedAttention: out = Q (Q^T Q) (K^T V) Q^T / 64  per (b,h) slice.
// Shapes: 16 head-slices of [N=2048, D=64], fp32 in, fp32 out [16, N, N].
#define NTOK 2048
#define DDIM 64
#define NHEAD 16          // B*H = 2*8
#define SEG 32            // N-segments for partial Gram reductions
#define RPS (NTOK / SEG)  // 64 rows per segment

typedef float f32x4 __attribute__((ext_vector_type(4)));
typedef short bf16x8 __attribute__((ext_vector_type(8)));
typedef unsigned short u16;

__device__ __forceinline__ u16 f2bf(float f) {
  union { float f; unsigned u; } v; v.f = f;
  unsigned u = v.u;
  return (u16)((u + 0x7fffu + ((u >> 16) & 1u)) >> 16);  // RNE, no NaN here
}

// ---------------------------------------------------------------------------
// Kernel A: per (head, segment) partial M1 = Q^T Q and M2 = K^T V  (64x64 each)
// grid (16, 32), block 256
__global__ __launch_bounds__(256) void k_partials(
    const float* __restrict__ Q, const float* __restrict__ Kp,
    const float* __restrict__ V, float* __restrict__ P1, float* __restrict__ P2) {
  const int h = blockIdx.x, s = blockIdx.y;
  const int t = threadIdx.x;
  const size_t base = (size_t)h * NTOK * DDIM + (size_t)s * RPS * DDIM;

  __shared__ float Qs[RPS][DDIM];  // 16 KB each, 48 KB total
  __shared__ float Ks[RPS][DDIM];
  __shared__ float Vs[RPS][DDIM];

  for (int i = t; i < RPS * DDIM / 4; i += 256) {
    ((float4*)Qs)[i] = ((const float4*)(Q + base))[i];
    ((float4*)Ks)[i] = ((const float4*)(Kp + base))[i];
    ((float4*)Vs)[i] = ((const float4*)(V + base))[i];
  }
  __syncthreads();

  const int i0 = (t & 15) * 4, j0 = (t >> 4) * 4;  // thread owns 4x4 of 64x64
  float m1[4][4] = {{0}}, m2[4][4] = {{0}};
  for (int n = 0; n < RPS; n++) {
    f32x4 qi = *(const f32x4*)&Qs[n][i0];
    f32x4 qj = *(const f32x4*)&Qs[n][j0];
    f32x4 ki = *(const f32x4*)&Ks[n][i0];
    f32x4 vj = *(const f32x4*)&Vs[n][j0];
#pragma unroll
    for (int a = 0; a < 4; a++)
#pragma unroll
      for (int b = 0; b < 4; b++) {
        m1[a][b] += qi[a] * qj[b];
        m2[a][b] += ki[a] * vj[b];
      }
  }
  float* p1 = P1 + (size_t)(h * SEG + s) * 4096;
  float* p2 = P2 + (size_t)(h * SEG + s) * 4096;
#pragma unroll
  for (int a = 0; a < 4; a++)
#pragma unroll
    for (int b = 0; b < 4; b++) {
      p1[(i0 + a) * 64 + j0 + b] = m1[a][b];
      p2[(i0 + a) * 64 + j0 + b] = m2[a][b];
    }
}

// ---------------------------------------------------------------------------
// Kernel B1: reduce partials -> M1, M2; M3 = M1 @ M2 (64x64). grid 16, block 256
__global__ __launch_bounds__(256) void k_m3(
    const float* __restrict__ P1, const float* __restrict__ P2,
    float* __restrict__ M3) {
  const int h = blockIdx.x, t = threadIdx.x;
  __shared__ float M1s[64][65];  // padded: col reads stride-65 -> no conflict
  __shared__ float M2s[64][64];

  for (int j = 0; j < 16; j++) {
    int e = j * 256 + t;  // coalesced across lanes
    float s1 = 0.f, s2 = 0.f;
    for (int s = 0; s < SEG; s++) {
      s1 += P1[(size_t)(h * SEG + s) * 4096 + e];
      s2 += P2[(size_t)(h * SEG + s) * 4096 + e];
    }
    M1s[e >> 6][e & 63] = s1;
    M2s[e >> 6][e & 63] = s2;
  }
  __syncthreads();

  const int i = t & 63, j0 = (t >> 6) * 16;
  float acc[16] = {0};
  for (int k = 0; k < 64; k++) {
    float a = M1s[i][k];
    f32x4 b0 = *(const f32x4*)&M2s[k][j0 + 0];
    f32x4 b1 = *(const f32x4*)&M2s[k][j0 + 4];
    f32x4 b2 = *(const f32x4*)&M2s[k][j0 + 8];
    f32x4 b3 = *(const f32x4*)&M2s[k][j0 + 12];
#pragma unroll
    for (int j = 0; j < 4; j++) {
      acc[j + 0] += a * b0[j];
      acc[j + 4] += a * b1[j];
      acc[j + 8] += a * b2[j];
      acc[j + 12] += a * b3[j];
    }
  }
  float* m3 = M3 + (size_t)h * 4096 + (size_t)i * 64 + j0;
#pragma unroll
  for (int j = 0; j < 16; j++) m3[j] = acc[j];
}

// ---------------------------------------------------------------------------
// Kernel B2: T = (Q @ M3)/64 -> bf16, and Qb = bf16(Q). grid (16,32), block 256
__global__ __launch_bounds__(256) void k_T(
    const float* __restrict__ Q, const float* __restrict__ M3,
    u16* __restrict__ Tb, u16* __restrict__ Qb) {
  const int h = blockIdx.x, s = blockIdx.y, t = threadIdx.x;
  const size_t base = (size_t)h * NTOK * DDIM + (size_t)s * RPS * DDIM;

  __shared__ float M3s[64][64];
  __shared__ float Qs[64][65];  // padded for column reads

  for (int i = t; i < 1024; i += 256)
    ((f32x4*)M3s)[i] = ((const f32x4*)(M3 + (size_t)h * 4096))[i];
  for (int i = t; i < 4096; i += 256)
    Qs[i >> 6][i & 63] = Q[base + i];
  __syncthreads();

  const int n = t & 63, k0 = (t >> 6) * 16;
  float acc[16] = {0};
  for (int d = 0; d < 64; d++) {
    float q = Qs[n][d];
    f32x4 b0 = *(const f32x4*)&M3s[d][k0 + 0];
    f32x4 b1 = *(const f32x4*)&M3s[d][k0 + 4];
    f32x4 b2 = *(const f32x4*)&M3s[d][k0 + 8];
    f32x4 b3 = *(const f32x4*)&M3s[d][k0 + 12];
#pragma unroll
    for (int j = 0; j < 4; j++) {
      acc[j + 0] += q * b0[j];
      acc[j + 4] += q * b1[j];
      acc[j + 8] += q * b2[j];
      acc[j + 12] += q * b3[j];
    }
  }
  const float inv = 1.0f / 64.0f;
  u16* tb = Tb + base + (size_t)n * DDIM + k0;
  u16* qb = Qb + base + (size_t)n * DDIM + k0;
#pragma unroll
  for (int j = 0; j < 16; j++) tb[j] = f2bf(acc[j] * inv);
#pragma unroll
  for (int j = 0; j < 16; j++) qb[j] = f2bf(Qs[n][k0 + j]);
}

// ---------------------------------------------------------------------------
// Kernel C: out[h] = Tb[h] @ Qb[h]^T  (N x N, K=64), bf16 MFMA, fp32 out.
// grid (16,16,16): (bcol, brow, head); block 256 = 4 waves, 128x128 tile.
__global__ __launch_bounds__(256) void k_gemm(
    const u16* __restrict__ Tb, const u16* __restrict__ Qb,
    float* __restrict__ out) {
  const int h = blockIdx.z;
  const int brow = blockIdx.y * 128, bcol = blockIdx.x * 128;
  const int t = threadIdx.x, w = t >> 6, l = t & 63;
  const int wr = w >> 1, wc = w & 1;  // 2x2 waves, 64x64 each
  const int lr = l & 15, lk = l >> 4; // frag row, k-group

  const u16* Th = Tb + (size_t)h * NTOK * DDIM;
  const u16* Qh = Qb + (size_t)h * NTOK * DDIM;

  bf16x8 a[4][2];
#pragma unroll
  for (int mi = 0; mi < 4; mi++) {
    const int row = brow + wr * 64 + mi * 16 + lr;
    const u16* p = Th + (size_t)row * DDIM + lk * 8;
    a[mi][0] = *(const bf16x8*)p;
    a[mi][1] = *(const bf16x8*)(p + 32);
  }

  f32x4 acc[4][4] = {};
#pragma unroll
  for (int ni = 0; ni < 4; ni++) {
    const int col = bcol + wc * 64 + ni * 16 + lr;
    const u16* p = Qh + (size_t)col * DDIM + lk * 8;
    bf16x8 b0 = *(const bf16x8*)p;
    bf16x8 b1 = *(const bf16x8*)(p + 32);
#pragma unroll
    for (int mi = 0; mi < 4; mi++) {
      acc[mi][ni] = __builtin_amdgcn_mfma_f32_16x16x32_bf16(a[mi][0], b0, acc[mi][ni], 0, 0, 0);
      acc[mi][ni] = __builtin_amdgcn_mfma_f32_16x16x32_bf16(a[mi][1], b1, acc[mi][ni], 0, 0, 0);
    }
  }

  float* oh = out + (size_t)h * NTOK * NTOK;
#pragma unroll
  for (int mi = 0; mi < 4; mi++)
#pragma unroll
    for (int ni = 0; ni < 4; ni++) {
      const int r0 = brow + wr * 64 + mi * 16 + lk * 4;
      const int c = bcol + wc * 64 + ni * 16 + lr;
#pragma unroll
      for (int reg = 0; reg < 4; reg++)
        oh[(size_t)(r0 + reg) * NTOK + c] = acc[mi][ni][reg];
    }
}

// ---------------------------------------------------------------------------
extern "C" void kernel_launch(void* const* d_in, const int* in_sizes, int n_in,
                              void* d_out, int out_size, void* d_ws, size_t ws_size,
                              hipStream_t stream) {
  // inputs: X (dead), Q, K, V — each [2,8,2048,64] fp32
  const float* Q = (const float*)d_in[1];
  const float* K = (const float*)d_in[2];
  const float* V = (const float*)d_in[3];
  float* out = (float*)d_out;

  // workspace layout (needs ~25 MB)
  char* ws = (char*)d_ws;
  float* P1 = (float*)(ws);                      // 16*32*4096 f32 = 8 MB
  float* P2 = (float*)(ws + (8u << 20));         // 8 MB
  float* M3 = (float*)(ws + (16u << 20));        // 16*4096 f32 = 256 KB
  u16* Tb   = (u16*)(ws + (17u << 20));          // 16*2048*64 bf16 = 4 MB
  u16* Qb   = (u16*)(ws + (21u << 20));          // 4 MB

  k_partials<<<dim3(NHEAD, SEG), 256, 0, stream>>>(Q, K, V, P1, P2);
  k_m3<<<NHEAD, 256, 0, stream>>>(P1, P2, M3);
  k_T<<<dim3(NHEAD, SEG), 256, 0, stream>>>(Q, M3, Tb, Qb);
  k_gemm<<<dim3(NTOK / 128, NTOK / 128, NHEAD), 256, 0, stream>>>(Tb, Qb, out);
}

// Round 2
// 328.615 us; speedup vs baseline: 1.1663x; 1.1663x over previous
//
#include <hip/hip_runtime.h>

// DecomposedAttention: out = Q (Q^T Q) (K^T V) Q^T / 64  per (b,h) slice.
// Shapes: 16 head-slices of [N=2048, D=64], fp32 in, fp32 out [16, N, N].
#define NTOK 2048
#define DDIM 64
#define NHEAD 16          // B*H = 2*8
#define SEG 32            // N-segments for partial Gram reductions
#define RPS (NTOK / SEG)  // 64 rows per segment

typedef float f32x4 __attribute__((ext_vector_type(4)));
typedef short bf16x8 __attribute__((ext_vector_type(8)));
typedef short short8 __attribute__((ext_vector_type(8)));
typedef unsigned short u16;

__device__ __forceinline__ u16 f2bf(float f) {
  union { float f; unsigned u; } v; v.f = f;
  unsigned u = v.u;
  return (u16)((u + 0x7fffu + ((u >> 16) & 1u)) >> 16);  // RNE, no NaN here
}

// ---------------------------------------------------------------------------
// Kernel A: per (head, segment) partial M1 = Q^T Q and M2 = K^T V  (64x64 each)
// grid (16, 32), block 256
__global__ __launch_bounds__(256) void k_partials(
    const float* __restrict__ Q, const float* __restrict__ Kp,
    const float* __restrict__ V, float* __restrict__ P1, float* __restrict__ P2) {
  const int h = blockIdx.x, s = blockIdx.y;
  const int t = threadIdx.x;
  const size_t base = (size_t)h * NTOK * DDIM + (size_t)s * RPS * DDIM;

  __shared__ float Qs[RPS][DDIM];  // 16 KB each, 48 KB total
  __shared__ float Ks[RPS][DDIM];
  __shared__ float Vs[RPS][DDIM];

  for (int i = t; i < RPS * DDIM / 4; i += 256) {
    ((float4*)Qs)[i] = ((const float4*)(Q + base))[i];
    ((float4*)Ks)[i] = ((const float4*)(Kp + base))[i];
    ((float4*)Vs)[i] = ((const float4*)(V + base))[i];
  }
  __syncthreads();

  const int i0 = (t & 15) * 4, j0 = (t >> 4) * 4;  // thread owns 4x4 of 64x64
  float m1[4][4] = {{0}}, m2[4][4] = {{0}};
  for (int n = 0; n < RPS; n++) {
    f32x4 qi = *(const f32x4*)&Qs[n][i0];
    f32x4 qj = *(const f32x4*)&Qs[n][j0];
    f32x4 ki = *(const f32x4*)&Ks[n][i0];
    f32x4 vj = *(const f32x4*)&Vs[n][j0];
#pragma unroll
    for (int a = 0; a < 4; a++)
#pragma unroll
      for (int b = 0; b < 4; b++) {
        m1[a][b] += qi[a] * qj[b];
        m2[a][b] += ki[a] * vj[b];
      }
  }
  float* p1 = P1 + (size_t)(h * SEG + s) * 4096;
  float* p2 = P2 + (size_t)(h * SEG + s) * 4096;
#pragma unroll
  for (int a = 0; a < 4; a++)
#pragma unroll
    for (int b = 0; b < 4; b++) {
      p1[(i0 + a) * 64 + j0 + b] = m1[a][b];
      p2[(i0 + a) * 64 + j0 + b] = m2[a][b];
    }
}

// ---------------------------------------------------------------------------
// Kernel B: parallel reduction of partials -> M1, M2.
// grid (16, 16) = 256 blocks, block 256; each thread reduces ONE element
// of the 64x64 matrices across the 32 segments. Coalesced: per segment a
// block's 256 threads read 1 KB contiguous.
__global__ __launch_bounds__(256) void k_reduce(
    const float* __restrict__ P1, const float* __restrict__ P2,
    float* __restrict__ M1, float* __restrict__ M2) {
  const int h = blockIdx.x;
  const int e = blockIdx.y * 256 + threadIdx.x;  // element 0..4095
  const size_t base = (size_t)h * SEG * 4096 + e;
  float s1 = 0.f, s2 = 0.f;
#pragma unroll 8
  for (int s = 0; s < SEG; s++) {
    s1 += P1[base + (size_t)s * 4096];
    s2 += P2[base + (size_t)s * 4096];
  }
  M1[(size_t)h * 4096 + e] = s1;
  M2[(size_t)h * 4096 + e] = s2;
}

// ---------------------------------------------------------------------------
// Kernel C: per block, recompute M3 = M1 @ M2 (64x64, cheap, redundant x32),
// then T-strip = (Q_strip @ M3)/64 -> bf16, and Qb = bf16(Q_strip).
// grid (16, 32), block 256.
__global__ __launch_bounds__(256) void k_Tm3(
    const float* __restrict__ Q, const float* __restrict__ M1,
    const float* __restrict__ M2, u16* __restrict__ Tb, u16* __restrict__ Qb) {
  const int h = blockIdx.x, s = blockIdx.y, t = threadIdx.x;
  const size_t base = (size_t)h * NTOK * DDIM + (size_t)s * RPS * DDIM;

  __shared__ float M1s[64][65];  // pad 65: row-i scalar reads conflict-free
  __shared__ float M2s[64][64];  // row f32x4 broadcast reads
  __shared__ float M3s[64][68];  // pad 68: rows stay 16B-aligned for f32x4
  __shared__ float Qs[64][65];   // pad 65: column-ish reads conflict-free

  for (int i = t; i < 4096; i += 256) {
    M1s[i >> 6][i & 63] = M1[(size_t)h * 4096 + i];
    Qs[i >> 6][i & 63] = Q[base + i];
  }
  for (int i = t; i < 1024; i += 256)
    ((f32x4*)M2s)[i] = ((const f32x4*)(M2 + (size_t)h * 4096))[i];
  __syncthreads();

  // M3 = M1 @ M2 : thread (i, j0..j0+15)
  {
    const int i = t & 63, j0 = (t >> 6) * 16;
    float acc[16] = {0};
    for (int k = 0; k < 64; k++) {
      float a = M1s[i][k];
      f32x4 b0 = *(const f32x4*)&M2s[k][j0 + 0];
      f32x4 b1 = *(const f32x4*)&M2s[k][j0 + 4];
      f32x4 b2 = *(const f32x4*)&M2s[k][j0 + 8];
      f32x4 b3 = *(const f32x4*)&M2s[k][j0 + 12];
#pragma unroll
      for (int j = 0; j < 4; j++) {
        acc[j + 0] += a * b0[j];
        acc[j + 4] += a * b1[j];
        acc[j + 8] += a * b2[j];
        acc[j + 12] += a * b3[j];
      }
    }
#pragma unroll
    for (int j = 0; j < 16; j++) M3s[i][j0 + j] = acc[j];
  }
  __syncthreads();

  // T = (Q_strip @ M3)/64 : thread (row n, cols k0..k0+15)
  const int n = t & 63, k0 = (t >> 6) * 16;
  float acc[16] = {0};
  for (int d = 0; d < 64; d++) {
    float q = Qs[n][d];
    f32x4 b0 = *(const f32x4*)&M3s[d][k0 + 0];
    f32x4 b1 = *(const f32x4*)&M3s[d][k0 + 4];
    f32x4 b2 = *(const f32x4*)&M3s[d][k0 + 8];
    f32x4 b3 = *(const f32x4*)&M3s[d][k0 + 12];
#pragma unroll
    for (int j = 0; j < 4; j++) {
      acc[j + 0] += q * b0[j];
      acc[j + 4] += q * b1[j];
      acc[j + 8] += q * b2[j];
      acc[j + 12] += q * b3[j];
    }
  }
  const float inv = 1.0f / 64.0f;
  short8 tv0, tv1, qv0, qv1;
#pragma unroll
  for (int j = 0; j < 8; j++) {
    tv0[j] = (short)f2bf(acc[j] * inv);
    tv1[j] = (short)f2bf(acc[j + 8] * inv);
    qv0[j] = (short)f2bf(Qs[n][k0 + j]);
    qv1[j] = (short)f2bf(Qs[n][k0 + 8 + j]);
  }
  u16* tb = Tb + base + (size_t)n * DDIM + k0;
  u16* qb = Qb + base + (size_t)n * DDIM + k0;
  *(short8*)tb = tv0;
  *(short8*)(tb + 8) = tv1;
  *(short8*)qb = qv0;
  *(short8*)(qb + 8) = qv1;
}

// ---------------------------------------------------------------------------
// Kernel D: out[h] = Tb[h] @ Qb[h]^T  (N x N, K=64), bf16 MFMA, fp32 out.
// grid (16,16,16): (bcol, brow, head); block 256 = 4 waves, 128x128 tile.
// Write-bound: 256 MB fp32 output is the session floor (~43 us at 6.3 TB/s).
__global__ __launch_bounds__(256) void k_gemm(
    const u16* __restrict__ Tb, const u16* __restrict__ Qb,
    float* __restrict__ out) {
  const int h = blockIdx.z;
  const int brow = blockIdx.y * 128, bcol = blockIdx.x * 128;
  const int t = threadIdx.x, w = t >> 6, l = t & 63;
  const int wr = w >> 1, wc = w & 1;  // 2x2 waves, 64x64 each
  const int lr = l & 15, lk = l >> 4; // frag row, k-group

  const u16* Th = Tb + (size_t)h * NTOK * DDIM;
  const u16* Qh = Qb + (size_t)h * NTOK * DDIM;

  bf16x8 a[4][2];
#pragma unroll
  for (int mi = 0; mi < 4; mi++) {
    const int row = brow + wr * 64 + mi * 16 + lr;
    const u16* p = Th + (size_t)row * DDIM + lk * 8;
    a[mi][0] = *(const bf16x8*)p;
    a[mi][1] = *(const bf16x8*)(p + 32);
  }

  f32x4 acc[4][4] = {};
#pragma unroll
  for (int ni = 0; ni < 4; ni++) {
    const int col = bcol + wc * 64 + ni * 16 + lr;
    const u16* p = Qh + (size_t)col * DDIM + lk * 8;
    bf16x8 b0 = *(const bf16x8*)p;
    bf16x8 b1 = *(const bf16x8*)(p + 32);
#pragma unroll
    for (int mi = 0; mi < 4; mi++) {
      acc[mi][ni] = __builtin_amdgcn_mfma_f32_16x16x32_bf16(a[mi][0], b0, acc[mi][ni], 0, 0, 0);
      acc[mi][ni] = __builtin_amdgcn_mfma_f32_16x16x32_bf16(a[mi][1], b1, acc[mi][ni], 0, 0, 0);
    }
  }

  float* oh = out + (size_t)h * NTOK * NTOK;
#pragma unroll
  for (int mi = 0; mi < 4; mi++)
#pragma unroll
    for (int ni = 0; ni < 4; ni++) {
      const int r0 = brow + wr * 64 + mi * 16 + lk * 4;
      const int c = bcol + wc * 64 + ni * 16 + lr;
#pragma unroll
      for (int reg = 0; reg < 4; reg++)
        oh[(size_t)(r0 + reg) * NTOK + c] = acc[mi][ni][reg];
    }
}

// ---------------------------------------------------------------------------
extern "C" void kernel_launch(void* const* d_in, const int* in_sizes, int n_in,
                              void* d_out, int out_size, void* d_ws, size_t ws_size,
                              hipStream_t stream) {
  // inputs: X (dead), Q, K, V — each [2,8,2048,64] fp32
  const float* Q = (const float*)d_in[1];
  const float* K = (const float*)d_in[2];
  const float* V = (const float*)d_in[3];
  float* out = (float*)d_out;

  // workspace layout (~25 MB)
  char* ws = (char*)d_ws;
  float* P1 = (float*)(ws);                      // 16*32*4096 f32 = 8 MB
  float* P2 = (float*)(ws + (8u << 20));         // 8 MB
  float* M1 = (float*)(ws + (16u << 20));        // 16*4096 f32 = 256 KB
  float* M2 = (float*)(ws + (16u << 20) + (256u << 10));  // 256 KB
  u16* Tb   = (u16*)(ws + (17u << 20));          // 16*2048*64 bf16 = 4 MB
  u16* Qb   = (u16*)(ws + (21u << 20));          // 4 MB

  k_partials<<<dim3(NHEAD, SEG), 256, 0, stream>>>(Q, K, V, P1, P2);
  k_reduce<<<dim3(NHEAD, 16), 256, 0, stream>>>(P1, P2, M1, M2);
  k_Tm3<<<dim3(NHEAD, SEG), 256, 0, stream>>>(Q, M1, M2, Tb, Qb);
  k_gemm<<<dim3(NTOK / 128, NTOK / 128, NHEAD), 256, 0, stream>>>(Tb, Qb, out);
}